// Round 21
// baseline (35.800 us; speedup 1.0000x reference)
//
#include <hip/hip_runtime.h>
#include <hip/hip_bf16.h>

#define NROWS 8192
#define DCOLS 256
#define NPAIR 1040   // 2080 upper-triangle 128x128 tiles, 2 per block
constexpr float EPSV = 1e-6f;
constexpr float FP8_SCALE = 16.0f;
constexpr float GRAM_FIX = 2.0f / (FP8_SCALE * FP8_SCALE);

typedef __attribute__((ext_vector_type(4))) float f32x4;
typedef __attribute__((ext_vector_type(2))) long long ll2;

__device__ __forceinline__ void async16(void* lds, const void* g) {
    __builtin_amdgcn_global_load_lds(
        (const __attribute__((address_space(1))) void*)g,
        (__attribute__((address_space(3))) void*)lds, 16, 0, 0);
}

#define SBAR() do { __builtin_amdgcn_sched_barrier(0); __builtin_amdgcn_s_barrier(); \
                    __builtin_amdgcn_sched_barrier(0); } while (0)
#define VMWAIT(N) asm volatile("s_waitcnt vmcnt(" #N ")" ::: "memory")

// ---------------- K1: ONE pass -> fp8(16*e) packed, sqn=||e||^2, colsum partials ----------------
// 2048 blocks x 4 waves x 1 row/wave: max TLP, single butterfly chain per wave.
// Packed row layout (256B/row): byte(k) = (k>>6)*64 + (((k&31)>>3)<<4) + ((k>>5)&1)*8 + (k&7)
__global__ void k1_fused(const float* __restrict__ in,
                         unsigned char* __restrict__ cf8, float* __restrict__ sqn,
                         float* __restrict__ part) {
    int t = threadIdx.x, lane = t & 63, wave = t >> 6;
    int row = blockIdx.x * 4 + wave;
    __shared__ float cs[4][256];
    int k0 = lane * 4;
    int s4 = k0 >> 6, kp = k0 & 63, h = kp >> 5, kpp = kp & 31;
    int pos = s4 * 64 + ((kpp >> 3) << 4) + h * 8 + (kpp & 7);   // per-lane constant

    float4 v = *reinterpret_cast<const float4*>(&in[row * DCOLS + k0]);
    float s = v.x * v.x + v.y * v.y + v.z * v.z + v.w * v.w;
    #pragma unroll
    for (int o = 1; o < 64; o <<= 1) s += __shfl_xor(s, o);
    float iv = 1.0f / (sqrtf(s) + EPSV);
    if (lane == 0) sqn[row] = s * iv * iv;     // ||e||^2 after normalization
    float4 ev = {v.x * iv, v.y * iv, v.z * iv, v.w * iv};
    int pk = __builtin_amdgcn_cvt_pk_fp8_f32(ev.x * FP8_SCALE, ev.y * FP8_SCALE, 0, false);
    pk = __builtin_amdgcn_cvt_pk_fp8_f32(ev.z * FP8_SCALE, ev.w * FP8_SCALE, pk, true);
    *reinterpret_cast<int*>(&cf8[row * DCOLS + pos]) = pk;

    *reinterpret_cast<float4*>(&cs[wave][lane * 4]) = ev;
    __syncthreads();
    part[blockIdx.x * 256 + t] = cs[0][t] + cs[1][t] + cs[2][t] + cs[3][t];
}

// ---------------- KMID: reduce 2048 partial rows -> 64 ----------------
__global__ void kmid(const float* __restrict__ part, float* __restrict__ part2) {
    int t = threadIdx.x;
    float m = 0.f;
    #pragma unroll 8
    for (int i = 0; i < 32; ++i) m += part[(blockIdx.x * 32 + i) * 256 + t];
    part2[blockIdx.x * 256 + t] = m;
}

// ---------------- K4: r20-verbatim. paired 128x128 fp8 tiles, 8 waves, counted-vmcnt dbuf + setprio ----------------
__device__ __forceinline__ void compute_slice(const unsigned char* Ar, const unsigned char* Br,
                                              int aBase, int bBase, f32x4 acc[4][2]) {
    ll2 a[4], b[2];
    #pragma unroll
    for (int m = 0; m < 4; ++m)
        a[m] = *reinterpret_cast<const ll2*>(Ar + aBase + m * 1024);
    #pragma unroll
    for (int n = 0; n < 2; ++n)
        b[n] = *reinterpret_cast<const ll2*>(Br + bBase + n * 1024);
    __builtin_amdgcn_s_setprio(1);
    #pragma unroll
    for (int m = 0; m < 4; ++m)
        #pragma unroll
        for (int n = 0; n < 2; ++n) {
            acc[m][n] = __builtin_amdgcn_mfma_f32_16x16x32_fp8_fp8(a[m].x, b[n].x, acc[m][n], 0, 0, 0);
            acc[m][n] = __builtin_amdgcn_mfma_f32_16x16x32_fp8_fp8(a[m].y, b[n].y, acc[m][n], 0, 0, 0);
        }
    __builtin_amdgcn_s_setprio(0);
}

__global__ __launch_bounds__(512, 4) void k4_dist(const unsigned char* __restrict__ cf8,
                                                  const float* __restrict__ sqn,
                                                  float* __restrict__ partial) {
    __shared__ unsigned char As[2][128 * 64];   // 2 x 8KB
    __shared__ unsigned char Bs[2][128 * 64];
    __shared__ float sqA[2][128], sqB[2][128];
    __shared__ float red8[8];

    int bid = blockIdx.x;
    int j = (bid & 7) * (NPAIR / 8) + (bid >> 3);   // XCD swizzle, 1040%8==0
    int idx0 = 2 * j;
    int q0 = (int)((sqrtf(8.0f * (float)idx0 + 1.0f) - 1.0f) * 0.5f);
    while ((q0 + 1) * (q0 + 2) / 2 <= idx0) ++q0;
    while (q0 * (q0 + 1) / 2 > idx0) --q0;
    int p0 = idx0 - q0 * (q0 + 1) / 2;
    int p1, q1;
    if (p0 < q0) { p1 = p0 + 1; q1 = q0; } else { p1 = 0; q1 = q0 + 1; }

    int t = threadIdx.x, lane = t & 63, wave = t >> 6;
    int wr = wave >> 2, wc = wave & 3;   // 2x4 grid: 64x32 per wave
    int rl = lane & 15, y = lane >> 4;

    int Rw = wave * 16;
    int laneOff = ((lane >> 2) * DCOLS) + ((((lane & 3) ^ ((lane >> 3) & 3))) << 4);
    const char* gbase = (const char*)cf8;
    const char* A0p = gbase + (size_t)(p0 * 128 + Rw) * DCOLS + laneOff;
    const char* B0p = gbase + (size_t)(q0 * 128 + Rw) * DCOLS + laneOff;
    const char* A1p = gbase + (size_t)(p1 * 128 + Rw) * DCOLS + laneOff;
    const char* B1p = gbase + (size_t)(q1 * 128 + Rw) * DCOLS + laneOff;

    int xc = y ^ ((rl >> 1) & 3);
    int aBase = (wr * 64 + rl) * 64 + xc * 16;
    int bBase = (wc * 32 + rl) * 64 + xc * 16;

    if (t < 128) sqA[0][t] = sqn[p0 * 128 + t];
    else if (t < 256) sqB[0][t - 128] = sqn[q0 * 128 + t - 128];
    else if (t < 384) sqA[1][t - 256] = sqn[p1 * 128 + t - 256];
    else sqB[1][t - 384] = sqn[q1 * 128 + t - 384];

    f32x4 acc[4][2] = {};
    float tsum = 0.0f;

#define STG(buf, Ap, Bp, off) do { \
        async16(&As[buf][Rw * 64], (Ap) + (off)); \
        async16(&Bs[buf][Rw * 64], (Bp) + (off)); } while (0)

#define EPILOGUE(ti, wfac) do { \
        float local = 0.0f; \
        _Pragma("unroll") \
        for (int n = 0; n < 2; ++n) { \
            float sj = sqB[ti][wc * 32 + n * 16 + rl]; \
            _Pragma("unroll") \
            for (int m = 0; m < 4; ++m) { \
                int i0 = wr * 64 + m * 16 + y * 4; \
                _Pragma("unroll") \
                for (int r = 0; r < 4; ++r) { \
                    float sq = sqA[ti][i0 + r] + sj - GRAM_FIX * acc[m][n][r]; \
                    local += __builtin_amdgcn_sqrtf(fmaxf(sq, 0.0f)); \
                } \
            } \
        } \
        tsum += (wfac) * local; } while (0)

    // ---- tile 0 ----
    STG(0, A0p, B0p, 0);
    STG(1, A0p, B0p, 64);
    __syncthreads();                                   // drains everything

    compute_slice(As[0], Bs[0], aBase, bBase, acc);    // t0 s0
    SBAR();
    STG(0, A0p, B0p, 128);
    compute_slice(As[1], Bs[1], aBase, bBase, acc);    // t0 s1
    SBAR();
    STG(1, A0p, B0p, 192);
    VMWAIT(2); SBAR();
    compute_slice(As[0], Bs[0], aBase, bBase, acc);    // t0 s2
    VMWAIT(0); SBAR();
    STG(0, A1p, B1p, 0);                               // t1 s0 flies under s3+epi
    compute_slice(As[1], Bs[1], aBase, bBase, acc);    // t0 s3
    EPILOGUE(0, (p0 == q0) ? 1.0f : 2.0f);
    #pragma unroll
    for (int m = 0; m < 4; ++m)
        #pragma unroll
        for (int n = 0; n < 2; ++n) acc[m][n] = f32x4{0.f, 0.f, 0.f, 0.f};
    SBAR();                                            // b1 free
    STG(1, A1p, B1p, 64);                              // t1 s1
    VMWAIT(2); SBAR();                                 // t1 s0 landed
    // ---- tile 1 ----
    compute_slice(As[0], Bs[0], aBase, bBase, acc);    // t1 s0
    SBAR();
    STG(0, A1p, B1p, 128);
    VMWAIT(2); SBAR();                                 // t1 s1 landed
    compute_slice(As[1], Bs[1], aBase, bBase, acc);    // t1 s1
    SBAR();
    STG(1, A1p, B1p, 192);
    VMWAIT(2); SBAR();                                 // t1 s2 landed
    compute_slice(As[0], Bs[0], aBase, bBase, acc);    // t1 s2
    VMWAIT(0); SBAR();                                 // t1 s3 landed
    compute_slice(As[1], Bs[1], aBase, bBase, acc);    // t1 s3
    EPILOGUE(1, (p1 == q1) ? 1.0f : 2.0f);
#undef STG
#undef EPILOGUE

    #pragma unroll
    for (int o = 1; o < 64; o <<= 1) tsum += __shfl_xor(tsum, o);
    if (lane == 0) red8[wave] = tsum;
    __syncthreads();
    if (t == 0) {
        float s8 = 0.f;
        #pragma unroll
        for (int i = 0; i < 8; ++i) s8 += red8[i];
        partial[j] = s8;
    }
}

// ---------------- K5: final scalar (+ ||mean||^2 from colsum partials) ----------------
__global__ void k5_final(const float* __restrict__ sqn, const float* __restrict__ partial,
                         const float* __restrict__ part2, float* __restrict__ out) {
    int t = threadIdx.x;
    int lane = t & 63, wave = t >> 6;
    float s = 0.0f;
    for (int r = t; r < NROWS; r += 1024) s += sqn[r];
    double ds = 0.0;
    for (int r = t; r < NPAIR; r += 1024) ds += (double)partial[r];
    #pragma unroll
    for (int o = 1; o < 64; o <<= 1) { s += __shfl_xor(s, o); ds += __shfl_xor(ds, o); }
    __shared__ float redf[16];
    __shared__ double redd[16];
    __shared__ float cls[4][256];
    __shared__ float redm[4];
    if (lane == 0) { redf[wave] = s; redd[wave] = ds; }
    // colmean: col = t&255, quarter qt = t>>8 covers 16 of the 64 part2 rows
    {
        int col = t & 255, qt = t >> 8;
        float cm = 0.f;
        #pragma unroll
        for (int i = 0; i < 16; ++i) cm += part2[(qt * 16 + i) * 256 + col];
        cls[qt][col] = cm;
    }
    __syncthreads();
    if (t < 256) {
        float c = cls[0][t] + cls[1][t] + cls[2][t] + cls[3][t];
        float mn = c * (1.0f / NROWS);
        float msqp = mn * mn;
        #pragma unroll
        for (int o = 1; o < 64; o <<= 1) msqp += __shfl_xor(msqp, o);
        if (lane == 0) redm[wave] = msqp;
    }
    __syncthreads();
    if (t == 0) {
        float sumsq = 0.f; double sd = 0.0;
        #pragma unroll
        for (int i = 0; i < 16; ++i) { sumsq += redf[i]; sd += redd[i]; }
        float msq = redm[0] + redm[1] + redm[2] + redm[3];
        float diagsum = sumsq - (float)NROWS * msq;   // sum over all c*c
        double md = sd / ((double)NROWS * (double)NROWS);
        out[0] = (float)DCOLS / diagsum + (float)log(md);
    }
}

extern "C" void kernel_launch(void* const* d_in, const int* in_sizes, int n_in,
                              void* d_out, int out_size, void* d_ws, size_t ws_size,
                              hipStream_t stream) {
    const float* emb = (const float*)d_in[0];
    float* out = (float*)d_out;
    char* ws = (char*)d_ws;

    float*  sqn     = (float*)(ws + 36864);            // 8192 f32
    float*  partial = (float*)(ws + 69632);            // 1040 f32
    float*  part    = (float*)(ws + 81920);            // 2048*256 f32 = 2MB
    float*  part2   = (float*)(ws + 81920 + 2097152);  // 64*256 f32
    unsigned char* cf8 = (unsigned char*)(ws + 81920 + 2097152 + 65536); // 2MB packed fp8

    k1_fused <<<2048, 256, 0, stream>>>(emb, cf8, sqn, part);
    kmid     <<<64, 256, 0, stream>>>(part, part2);
    k4_dist  <<<NPAIR, 512, 0, stream>>>(cf8, sqn, partial);
    k5_final <<<1, 1024, 0, stream>>>(sqn, partial, part2, out);
}

// Round 22
// 34.284 us; speedup vs baseline: 1.0442x; 1.0442x over previous
//
#include <hip/hip_runtime.h>
#include <hip/hip_bf16.h>

#define NROWS 8192
#define DCOLS 256
#define NPAIR 1040   // 2080 upper-triangle 128x128 tiles, 2 per block
constexpr float EPSV = 1e-6f;
constexpr float FP8_SCALE = 16.0f;
constexpr float GRAM_FIX = 2.0f / (FP8_SCALE * FP8_SCALE);

typedef __attribute__((ext_vector_type(4))) float f32x4;
typedef __attribute__((ext_vector_type(2))) long long ll2;

__device__ __forceinline__ void async16(void* lds, const void* g) {
    __builtin_amdgcn_global_load_lds(
        (const __attribute__((address_space(1))) void*)g,
        (__attribute__((address_space(3))) void*)lds, 16, 0, 0);
}

#define SBAR() do { __builtin_amdgcn_sched_barrier(0); __builtin_amdgcn_s_barrier(); \
                    __builtin_amdgcn_sched_barrier(0); } while (0)
#define VMWAIT(N) asm volatile("s_waitcnt vmcnt(" #N ")" ::: "memory")

// ---------------- K1: ONE pass -> fp8(16*e) packed, sqn=||e||^2, colsum partials ----------------
// (centering cancels in pairwise distances: c_i - c_j = e_i - e_j; mean only needed for
//  diag_var = (sum||e||^2 - N*||mean||^2)/D, handled in k5 via colsum partials.)
// Packed row layout (256B/row): byte(k) = (k>>6)*64 + (((k&31)>>3)<<4) + ((k>>5)&1)*8 + (k&7)
__global__ void k1_fused(const float* __restrict__ in,
                         unsigned char* __restrict__ cf8, float* __restrict__ sqn,
                         float* __restrict__ part) {
    int t = threadIdx.x, lane = t & 63, wave = t >> 6;
    int r0 = blockIdx.x * 8;
    __shared__ float cs[4][256];
    int k0 = lane * 4;
    int s4 = k0 >> 6, kp = k0 & 63, h = kp >> 5, kpp = kp & 31;
    int pos = s4 * 64 + ((kpp >> 3) << 4) + h * 8 + (kpp & 7);   // per-lane constant
    float4 acc4 = {0.f, 0.f, 0.f, 0.f};
    #pragma unroll
    for (int rr = 0; rr < 2; ++rr) {
        int row = r0 + wave * 2 + rr;
        float4 v = *reinterpret_cast<const float4*>(&in[row * DCOLS + k0]);
        float s = v.x * v.x + v.y * v.y + v.z * v.z + v.w * v.w;
        #pragma unroll
        for (int o = 1; o < 64; o <<= 1) s += __shfl_xor(s, o);
        float iv = 1.0f / (sqrtf(s) + EPSV);
        if (lane == 0) sqn[row] = s * iv * iv;     // ||e||^2
        float4 ev = {v.x * iv, v.y * iv, v.z * iv, v.w * iv};
        int pk = __builtin_amdgcn_cvt_pk_fp8_f32(ev.x * FP8_SCALE, ev.y * FP8_SCALE, 0, false);
        pk = __builtin_amdgcn_cvt_pk_fp8_f32(ev.z * FP8_SCALE, ev.w * FP8_SCALE, pk, true);
        *reinterpret_cast<int*>(&cf8[row * DCOLS + pos]) = pk;
        acc4.x += ev.x; acc4.y += ev.y; acc4.z += ev.z; acc4.w += ev.w;
    }
    *reinterpret_cast<float4*>(&cs[wave][lane * 4]) = acc4;
    __syncthreads();
    part[blockIdx.x * 256 + t] = cs[0][t] + cs[1][t] + cs[2][t] + cs[3][t];
}

// ---------------- KMID: reduce 1024 partial rows -> 64 ----------------
__global__ void kmid(const float* __restrict__ part, float* __restrict__ part2) {
    int t = threadIdx.x;
    float m = 0.f;
    #pragma unroll
    for (int i = 0; i < 16; ++i) m += part[(blockIdx.x * 16 + i) * 256 + t];
    part2[blockIdx.x * 256 + t] = m;
}

// ---------------- K4: paired 128x128 fp8 tiles, 8 waves, counted-vmcnt dbuf + setprio ----------------
__device__ __forceinline__ void compute_slice(const unsigned char* Ar, const unsigned char* Br,
                                              int aBase, int bBase, f32x4 acc[4][2]) {
    ll2 a[4], b[2];
    #pragma unroll
    for (int m = 0; m < 4; ++m)
        a[m] = *reinterpret_cast<const ll2*>(Ar + aBase + m * 1024);
    #pragma unroll
    for (int n = 0; n < 2; ++n)
        b[n] = *reinterpret_cast<const ll2*>(Br + bBase + n * 1024);
    __builtin_amdgcn_s_setprio(1);
    #pragma unroll
    for (int m = 0; m < 4; ++m)
        #pragma unroll
        for (int n = 0; n < 2; ++n) {
            acc[m][n] = __builtin_amdgcn_mfma_f32_16x16x32_fp8_fp8(a[m].x, b[n].x, acc[m][n], 0, 0, 0);
            acc[m][n] = __builtin_amdgcn_mfma_f32_16x16x32_fp8_fp8(a[m].y, b[n].y, acc[m][n], 0, 0, 0);
        }
    __builtin_amdgcn_s_setprio(0);
}

__global__ __launch_bounds__(512, 4) void k4_dist(const unsigned char* __restrict__ cf8,
                                                  const float* __restrict__ sqn,
                                                  float* __restrict__ partial) {
    __shared__ unsigned char As[2][128 * 64];   // 2 x 8KB
    __shared__ unsigned char Bs[2][128 * 64];
    __shared__ float sqA[2][128], sqB[2][128];
    __shared__ float red8[8];

    int bid = blockIdx.x;
    int j = (bid & 7) * (NPAIR / 8) + (bid >> 3);   // XCD swizzle, 1040%8==0
    int idx0 = 2 * j;
    int q0 = (int)((sqrtf(8.0f * (float)idx0 + 1.0f) - 1.0f) * 0.5f);
    while ((q0 + 1) * (q0 + 2) / 2 <= idx0) ++q0;
    while (q0 * (q0 + 1) / 2 > idx0) --q0;
    int p0 = idx0 - q0 * (q0 + 1) / 2;
    int p1, q1;
    if (p0 < q0) { p1 = p0 + 1; q1 = q0; } else { p1 = 0; q1 = q0 + 1; }

    int t = threadIdx.x, lane = t & 63, wave = t >> 6;
    int wr = wave >> 2, wc = wave & 3;   // 2x4 grid: 64x32 per wave
    int rl = lane & 15, y = lane >> 4;

    int Rw = wave * 16;
    int laneOff = ((lane >> 2) * DCOLS) + ((((lane & 3) ^ ((lane >> 3) & 3))) << 4);
    const char* gbase = (const char*)cf8;
    const char* A0p = gbase + (size_t)(p0 * 128 + Rw) * DCOLS + laneOff;
    const char* B0p = gbase + (size_t)(q0 * 128 + Rw) * DCOLS + laneOff;
    const char* A1p = gbase + (size_t)(p1 * 128 + Rw) * DCOLS + laneOff;
    const char* B1p = gbase + (size_t)(q1 * 128 + Rw) * DCOLS + laneOff;

    int xc = y ^ ((rl >> 1) & 3);
    int aBase = (wr * 64 + rl) * 64 + xc * 16;
    int bBase = (wc * 32 + rl) * 64 + xc * 16;

    if (t < 128) sqA[0][t] = sqn[p0 * 128 + t];
    else if (t < 256) sqB[0][t - 128] = sqn[q0 * 128 + t - 128];
    else if (t < 384) sqA[1][t - 256] = sqn[p1 * 128 + t - 256];
    else sqB[1][t - 384] = sqn[q1 * 128 + t - 384];

    f32x4 acc[4][2] = {};
    float tsum = 0.0f;

#define STG(buf, Ap, Bp, off) do { \
        async16(&As[buf][Rw * 64], (Ap) + (off)); \
        async16(&Bs[buf][Rw * 64], (Bp) + (off)); } while (0)

#define EPILOGUE(ti, wfac) do { \
        float local = 0.0f; \
        _Pragma("unroll") \
        for (int n = 0; n < 2; ++n) { \
            float sj = sqB[ti][wc * 32 + n * 16 + rl]; \
            _Pragma("unroll") \
            for (int m = 0; m < 4; ++m) { \
                int i0 = wr * 64 + m * 16 + y * 4; \
                _Pragma("unroll") \
                for (int r = 0; r < 4; ++r) { \
                    float sq = sqA[ti][i0 + r] + sj - GRAM_FIX * acc[m][n][r]; \
                    local += __builtin_amdgcn_sqrtf(fmaxf(sq, 0.0f)); \
                } \
            } \
        } \
        tsum += (wfac) * local; } while (0)

    // ---- tile 0 ----
    STG(0, A0p, B0p, 0);
    STG(1, A0p, B0p, 64);
    __syncthreads();                                   // drains everything

    compute_slice(As[0], Bs[0], aBase, bBase, acc);    // t0 s0
    SBAR();
    STG(0, A0p, B0p, 128);
    compute_slice(As[1], Bs[1], aBase, bBase, acc);    // t0 s1
    SBAR();
    STG(1, A0p, B0p, 192);
    VMWAIT(2); SBAR();
    compute_slice(As[0], Bs[0], aBase, bBase, acc);    // t0 s2
    VMWAIT(0); SBAR();
    STG(0, A1p, B1p, 0);                               // t1 s0 flies under s3+epi
    compute_slice(As[1], Bs[1], aBase, bBase, acc);    // t0 s3
    EPILOGUE(0, (p0 == q0) ? 1.0f : 2.0f);
    #pragma unroll
    for (int m = 0; m < 4; ++m)
        #pragma unroll
        for (int n = 0; n < 2; ++n) acc[m][n] = f32x4{0.f, 0.f, 0.f, 0.f};
    SBAR();                                            // b1 free
    STG(1, A1p, B1p, 64);                              // t1 s1
    VMWAIT(2); SBAR();                                 // t1 s0 landed
    // ---- tile 1 ----
    compute_slice(As[0], Bs[0], aBase, bBase, acc);    // t1 s0
    SBAR();
    STG(0, A1p, B1p, 128);
    VMWAIT(2); SBAR();                                 // t1 s1 landed
    compute_slice(As[1], Bs[1], aBase, bBase, acc);    // t1 s1
    SBAR();
    STG(1, A1p, B1p, 192);
    VMWAIT(2); SBAR();                                 // t1 s2 landed
    compute_slice(As[0], Bs[0], aBase, bBase, acc);    // t1 s2
    VMWAIT(0); SBAR();                                 // t1 s3 landed
    compute_slice(As[1], Bs[1], aBase, bBase, acc);    // t1 s3
    EPILOGUE(1, (p1 == q1) ? 1.0f : 2.0f);
#undef STG
#undef EPILOGUE

    #pragma unroll
    for (int o = 1; o < 64; o <<= 1) tsum += __shfl_xor(tsum, o);
    if (lane == 0) red8[wave] = tsum;
    __syncthreads();
    if (t == 0) {
        float s8 = 0.f;
        #pragma unroll
        for (int i = 0; i < 8; ++i) s8 += red8[i];
        partial[j] = s8;
    }
}

// ---------------- K5: final scalar (+ ||mean||^2 from colsum partials) ----------------
__global__ void k5_final(const float* __restrict__ sqn, const float* __restrict__ partial,
                         const float* __restrict__ part2, float* __restrict__ out) {
    int t = threadIdx.x;
    int lane = t & 63, wave = t >> 6;
    float s = 0.0f;
    for (int r = t; r < NROWS; r += 1024) s += sqn[r];
    double ds = 0.0;
    for (int r = t; r < NPAIR; r += 1024) ds += (double)partial[r];
    #pragma unroll
    for (int o = 1; o < 64; o <<= 1) { s += __shfl_xor(s, o); ds += __shfl_xor(ds, o); }
    __shared__ float redf[16];
    __shared__ double redd[16];
    __shared__ float cls[4][256];
    __shared__ float redm[4];
    if (lane == 0) { redf[wave] = s; redd[wave] = ds; }
    // colmean: col = t&255, quarter qt = t>>8 covers 16 of the 64 part2 rows
    {
        int col = t & 255, qt = t >> 8;
        float cm = 0.f;
        #pragma unroll
        for (int i = 0; i < 16; ++i) cm += part2[(qt * 16 + i) * 256 + col];
        cls[qt][col] = cm;
    }
    __syncthreads();
    if (t < 256) {
        float c = cls[0][t] + cls[1][t] + cls[2][t] + cls[3][t];
        float mn = c * (1.0f / NROWS);
        float msqp = mn * mn;
        #pragma unroll
        for (int o = 1; o < 64; o <<= 1) msqp += __shfl_xor(msqp, o);
        if (lane == 0) redm[wave] = msqp;
    }
    __syncthreads();
    if (t == 0) {
        float sumsq = 0.f; double sd = 0.0;
        #pragma unroll
        for (int i = 0; i < 16; ++i) { sumsq += redf[i]; sd += redd[i]; }
        float msq = redm[0] + redm[1] + redm[2] + redm[3];
        float diagsum = sumsq - (float)NROWS * msq;   // sum over all c*c
        double md = sd / ((double)NROWS * (double)NROWS);
        out[0] = (float)DCOLS / diagsum + (float)log(md);
    }
}

extern "C" void kernel_launch(void* const* d_in, const int* in_sizes, int n_in,
                              void* d_out, int out_size, void* d_ws, size_t ws_size,
                              hipStream_t stream) {
    const float* emb = (const float*)d_in[0];
    float* out = (float*)d_out;
    char* ws = (char*)d_ws;

    float*  sqn     = (float*)(ws + 36864);          // 8192 f32
    float*  partial = (float*)(ws + 69632);          // 1040 f32
    float*  part    = (float*)(ws + 81920);          // 1024*256 f32 = 1MB
    float*  part2   = (float*)(ws + 81920 + 1048576);// 64*256 f32
    unsigned char* cf8 = (unsigned char*)(ws + 81920 + 1048576 + 65536); // 2MB packed fp8

    k1_fused <<<1024, 256, 0, stream>>>(emb, cf8, sqn, part);
    kmid     <<<64, 256, 0, stream>>>(part, part2);
    k4_dist  <<<NPAIR, 512, 0, stream>>>(cf8, sqn, partial);
    k5_final <<<1, 1024, 0, stream>>>(sqn, partial, part2, out);
}